// Round 10
// baseline (189.620 us; speedup 1.0000x reference)
//
#include <hip/hip_runtime.h>
#include <stdint.h>

typedef int v4i __attribute__((ext_vector_type(4)));
typedef float v4f __attribute__((ext_vector_type(4)));

#define BN 32
#define CI 32
#define CO 64
#define HH 224
#define WW 224

#define AMAX_BLOCKS 2048

static const size_t QW_BYTES  = 3 * 64 * 128;        // plain [kh][cout][k], K padded to 128 (pad zero)
static const size_t AMAX_OFF  = QW_BYTES;            // [0]=amax_x bits (atomicMax), [1]=amax_w float
static const size_t QX_OFF    = 32768;               // int8 NHWC qx, 51,380,224 B

// XOR swizzle for the conv x-tile (byte addr bits 4-6 ^= bits 7-9).
// Keeps 16B chunks intact so A-fragment ds_read_b128 stays aligned.
__device__ __forceinline__ int swz(int o) { return o ^ ((o >> 3) & 0x70); }

// ---------------- pass 1: x abs-max -> atomicMax on int-viewed float bits ----------------
// nonneg floats: int compare == float compare; order-independent -> deterministic;
// 0xAAAAAAAA ws-poison is negative -> always loses; replay-stale value equals same max.
__global__ __launch_bounds__(256) void k_amax(const float4* __restrict__ x4, long n4,
                                              float* __restrict__ amax_pair) {
    int t = threadIdx.x;
    float m = 0.f;
    long i = (long)blockIdx.x * blockDim.x + t;
    long stride = (long)AMAX_BLOCKS * blockDim.x;
    for (; i < n4; i += stride) {
        float4 v = x4[i];
        m = fmaxf(m, fmaxf(fmaxf(fabsf(v.x), fabsf(v.y)), fmaxf(fabsf(v.z), fabsf(v.w))));
    }
    for (int o = 32; o > 0; o >>= 1) m = fmaxf(m, __shfl_xor(m, o));
    __shared__ float sm[4];
    if ((t & 63) == 0) sm[t >> 6] = m;
    __syncthreads();
    if (t == 0) {
        m = fmaxf(fmaxf(sm[0], sm[1]), fmaxf(sm[2], sm[3]));
        atomicMax((int*)amax_pair, __float_as_int(m));
    }
}

// ---------------- pass 2: quantize x -> qx NHWC (blocks 0..7167), w -> qw (block 7168) ----
__global__ __launch_bounds__(256) void k_qxw(const float* __restrict__ x,
                                             const float* __restrict__ w,
                                             signed char* __restrict__ qx,
                                             signed char* __restrict__ qw,
                                             float* __restrict__ amax_pair) {
    int b = blockIdx.x;
    int t = threadIdx.x;
    if (b < BN * HH) {
        // quantize one (n,h) plane: NCHW fp32 -> NHWC int8 via LDS transpose (L3-hot reads)
        int h = b % HH;
        int n = b / HH;
        float s = 127.0f / __int_as_float(((const int*)amax_pair)[0]);
        __shared__ signed char ld[CI * 228];   // [ci][w], padded stride
        const float* xp = x + ((size_t)n * CI * HH + h) * WW;   // (ci,w) at xp[ci*HH*WW + w]
        for (int it = 0; it < 7; it++) {
            int idx = it * 256 + t;            // 1792 float4 tiles: ci in [0,32), w0 = 4*(idx%56)
            int ci = idx / 56;
            int w0 = (idx % 56) * 4;
            float4 v = *(const float4*)&xp[(size_t)ci * HH * WW + w0];
            float q0 = fminf(127.f, fmaxf(-127.f, rintf(v.x * s)));
            float q1 = fminf(127.f, fmaxf(-127.f, rintf(v.y * s)));
            float q2 = fminf(127.f, fmaxf(-127.f, rintf(v.z * s)));
            float q3 = fminf(127.f, fmaxf(-127.f, rintf(v.w * s)));
            int pk = ((int)q0 & 0xff) | (((int)q1 & 0xff) << 8) |
                     (((int)q2 & 0xff) << 16) | (((int)q3 & 0xff) << 24);
            *(int*)&ld[ci * 228 + w0] = pk;
        }
        __syncthreads();
        int* dst32 = (int*)(qx + ((size_t)n * HH + h) * WW * CI);
        for (int it = 0; it < 7; it++) {
            int idx = it * 256 + t;            // 1792 dwords of the (n,h) NHWC plane
            int ww_ = idx >> 3;
            int cig = idx & 7;
            int c0 = ld[(cig * 4 + 0) * 228 + ww_] & 0xff;
            int c1 = ld[(cig * 4 + 1) * 228 + ww_] & 0xff;
            int c2 = ld[(cig * 4 + 2) * 228 + ww_] & 0xff;
            int c3 = ld[(cig * 4 + 3) * 228 + ww_] & 0xff;
            dst32[idx] = c0 | (c1 << 8) | (c2 << 16) | (c3 << 24);
        }
        return;
    }

    // ---- block 7168: amax_w + quantize/rearrange weights ----
    __shared__ __align__(16) signed char qs[24576];
    __shared__ float smw[4];
    __shared__ float s_aw;
    for (int i = t; i < 1536; i += 256) ((v4i*)qs)[i] = (v4i){0, 0, 0, 0};

    float mw = 0.f;
    const float4* w4 = (const float4*)w;
    for (int i = t; i < 4608; i += 256) {
        float4 v = w4[i];
        mw = fmaxf(mw, fmaxf(fmaxf(fabsf(v.x), fabsf(v.y)), fmaxf(fabsf(v.z), fabsf(v.w))));
    }
    for (int o = 32; o > 0; o >>= 1) mw = fmaxf(mw, __shfl_xor(mw, o));
    if ((t & 63) == 0) smw[t >> 6] = mw;
    __syncthreads();
    if (t == 0) {
        s_aw = fmaxf(fmaxf(smw[0], smw[1]), fmaxf(smw[2], smw[3]));
        amax_pair[1] = s_aw;
    }
    __syncthreads();
    float s = 127.0f / s_aw;
    for (int i4 = t; i4 < 4608; i4 += 256) {
        float4 v = w4[i4];
        float e[4] = {v.x, v.y, v.z, v.w};
#pragma unroll
        for (int j = 0; j < 4; j++) {
            int idx = i4 * 4 + j;
            int kw = idx % 3;
            int kh = (idx / 3) % 3;
            int ci = (idx / 9) % 32;
            int o  = idx / 288;          // OIHW: ((o*32+ci)*3+kh)*3+kw
            float q = rintf(e[j] * s);
            q = fminf(127.f, fmaxf(-127.f, q));
            qs[kh * 8192 + o * 128 + kw * 32 + ci] = (signed char)q;
        }
    }
    __syncthreads();
    for (int i = t; i < 1536; i += 256) ((v4i*)qw)[i] = ((const v4i*)qs)[i];
}

// ---------------- conv: implicit GEMM over a 28-row strip, qx-fed ----------
// block = (n, w-half 112, 28 output rows). 4-row LDS ring (plain v4i copies from qx),
// weights in registers, per-wave epilogue patch, nontemporal stores. grid = 512.
__global__ __launch_bounds__(256) void k_conv(const signed char* __restrict__ qx,
                                              const signed char* __restrict__ qw,
                                              const float* __restrict__ bias,
                                              const float* __restrict__ amax_pair,
                                              float* __restrict__ out) {
    __shared__ __align__(16) signed char lds[4 * 120 * 32 + 4 * 16 * 116 * 4];  // ring 15360 + ep 29696
    float* ep = (float*)(lds + 15360);

    int b = blockIdx.x;
    int wt = b & 1;
    int hs = (b >> 1) & 7;
    int n = b >> 4;
    int w0 = wt * 112;
    int hstart = hs * 28;
    int t = threadIdx.x;
    int lane = t & 63;
    int wv = t >> 6;
    int r = lane & 15;
    int chunk = lane >> 4;
    int cout = wv * 16 + r;

    float ax = __int_as_float(((const int*)amax_pair)[0]);
    float aw = amax_pair[1];
    float invs = 1.0f / ((127.0f / ax) * (127.0f / aw));
    float bv = bias[cout];

    // B fragments: load once from global (L2-hot), no LDS
    v4i bf[3][2];
#pragma unroll
    for (int dh = 0; dh < 3; dh++)
#pragma unroll
        for (int s = 0; s < 2; s++)
            bf[dh][s] = *(const v4i*)&qw[dh * 8192 + cout * 128 + s * 64 + chunk * 16];

    // prologue: stage rows hstart-1 .. hstart+2 (960 tasks = 4 rows x 120 wl x 2 cih)
#pragma unroll
    for (int k = 0; k < 4; k++) {
        int task = t + k * 256;
        if (task < 960) {
            int cih = task & 1;
            int wl  = (task >> 1) % 120;
            int row = (task >> 1) / 120;
            int gh = hstart - 1 + row;
            int gw = w0 - 4 + wl;
            v4i v = (v4i){0, 0, 0, 0};
            if ((unsigned)gh < 224u && (unsigned)gw < 224u)
                v = *(const v4i*)&qx[(((size_t)n * HH + gh) * WW + gw) * CI + cih * 16];
            *(v4i*)&lds[swz((((gh & 3) * 120) + wl) * 32 + cih * 16)] = v;
        }
    }
    __syncthreads();

    float* epw = ep + wv * (16 * 116);

#pragma unroll 1
    for (int i = 0; i < 14; i++) {
        int h0 = hstart + 2 * i;
        bool pf = (i < 13);

        // T14 issue-early: loads for rows h0+3, h0+4 (480 tasks: t, and t+256 if t<224)
        v4i ldA = (v4i){0, 0, 0, 0}, ldB = (v4i){0, 0, 0, 0};
        int shA = 0, shB = 0;
        bool hasB = (t < 224);
        if (pf) {
            {
                int task = t;
                int cih = task & 1;
                int wl  = (task >> 1) % 120;
                int row = (task >> 1) / 120;
                int gh = h0 + 3 + row;
                int gw = w0 - 4 + wl;
                shA = swz((((gh & 3) * 120) + wl) * 32 + cih * 16);
                if ((unsigned)gh < 224u && (unsigned)gw < 224u)
                    ldA = *(const v4i*)&qx[(((size_t)n * HH + gh) * WW + gw) * CI + cih * 16];
            }
            if (hasB) {
                int task = t + 256;
                int cih = task & 1;
                int wl  = (task >> 1) % 120;
                int row = (task >> 1) / 120;
                int gh = h0 + 3 + row;
                int gw = w0 - 4 + wl;
                shB = swz((((gh & 3) * 120) + wl) * 32 + cih * 16);
                if ((unsigned)gh < 224u && (unsigned)gw < 224u)
                    ldB = *(const v4i*)&qx[(((size_t)n * HH + gh) * WW + gw) * CI + cih * 16];
            }
        }

        // MFMA: 14 m-tiles (2 rows x 7 w-subtiles) x 6 K-steps
        v4i acc[14];
#pragma unroll
        for (int m = 0; m < 14; m++) acc[m] = (v4i){0, 0, 0, 0};
#pragma unroll
        for (int dh = 0; dh < 3; dh++) {
#pragma unroll
            for (int s = 0; s < 2; s++) {
                int k16 = s * 64 + chunk * 16;
                int dw = k16 >> 5;
                if (dw > 2) dw = 2;          // pad K: B zero, A addr just valid
                int cih = (k16 >> 4) & 1;
#pragma unroll
                for (int m = 0; m < 14; m++) {
                    int gh = h0 - 1 + (m / 7) + dh;
                    int wl = 3 + (m % 7) * 16 + r + dw;
                    v4i af = *(const v4i*)&lds[swz((((gh & 3) * 120) + wl) * 32 + cih * 16)];
                    acc[m] = __builtin_amdgcn_mfma_i32_16x16x64_i8(af, bf[dh][s], acc[m], 0, 0, 0);
                }
            }
        }

        // epilogue: per-wave LDS patch transpose + nontemporal coalesced stores
#pragma unroll
        for (int half = 0; half < 2; half++) {
#pragma unroll
            for (int mm = 0; mm < 7; mm++) {
                int m = half * 7 + mm;
                float4 o;
                o.x = fmaf((float)acc[m][0], invs, bv);
                o.y = fmaf((float)acc[m][1], invs, bv);
                o.z = fmaf((float)acc[m][2], invs, bv);
                o.w = fmaf((float)acc[m][3], invs, bv);
                *(float4*)&epw[r * 116 + mm * 16 + chunk * 4] = o;
            }
            int hh = h0 + half;
#pragma unroll
            for (int it = 0; it < 7; it++) {
                int idx = it * 64 + lane;
                int co = idx / 28;           // wave-local cout
                int w4i_ = (idx % 28) * 4;
                v4f v = *(const v4f*)&epw[co * 116 + w4i_];
                __builtin_nontemporal_store(v,
                    (v4f*)&out[(((size_t)n * CO + wv * 16 + co) * HH + hh) * WW + w0 + w4i_]);
            }
        }

        __syncthreads();   // bar1: all waves done reading the two oldest ring slots

        // write-late: copy prefetched qx rows into ring slots (h0+3, h0+4)
        if (pf) {
            *(v4i*)&lds[shA] = ldA;
            if (hasB) *(v4i*)&lds[shB] = ldB;
        }
        __syncthreads();   // bar2: new slots visible before next iteration's MFMA
    }
}

extern "C" void kernel_launch(void* const* d_in, const int* in_sizes, int n_in,
                              void* d_out, int out_size, void* d_ws, size_t ws_size,
                              hipStream_t stream) {
    const float* x = (const float*)d_in[0];
    const float* w = (const float*)d_in[1];
    const float* bias = (const float*)d_in[2];
    float* out = (float*)d_out;

    signed char* qw = (signed char*)d_ws;
    float* amax_pair = (float*)((char*)d_ws + AMAX_OFF);
    signed char* qx = (signed char*)d_ws + QX_OFF;

    long n4 = (long)BN * CI * HH * WW / 4;
    k_amax<<<AMAX_BLOCKS, 256, 0, stream>>>((const float4*)x, n4, amax_pair);
    k_qxw<<<BN * HH + 1, 256, 0, stream>>>(x, w, qx, qw, amax_pair);
    k_conv<<<512, 256, 0, stream>>>(qx, qw, bias, amax_pair, out);
}

// Round 11
// 151.452 us; speedup vs baseline: 1.2520x; 1.2520x over previous
//
#include <hip/hip_runtime.h>
#include <stdint.h>

typedef int v4i __attribute__((ext_vector_type(4)));
typedef float v4f __attribute__((ext_vector_type(4)));

#define BN 32
#define CI 32
#define CO 64
#define HH 224
#define WW 224

#define AMAX_BLOCKS 2048

static const size_t QW_BYTES  = 3 * 64 * 128;        // plain [kh][cout][k], K padded to 128 (pad zero)
static const size_t AMAX_OFF  = QW_BYTES;            // 2 floats {amax_x, amax_w}
static const size_t PART_OFF  = AMAX_OFF + 128;      // 2048 partial-max floats

// XOR swizzle for the conv x-tile (byte addr bits 4-6 ^= bits 7-9).
// Keeps 16B chunks intact so A-fragment ds_read_b128 stays aligned.
__device__ __forceinline__ int swz(int o) { return o ^ ((o >> 3) & 0x70); }

// bar1: LDS-read hazard only; reads are complete via MFMA data-dependence before
// any wave arrives -> bare s_barrier, NO vmcnt(0) drain of the nt stores.
__device__ __forceinline__ void bar_nodrain() {
    __builtin_amdgcn_sched_barrier(0);
    __builtin_amdgcn_s_barrier();
    __builtin_amdgcn_sched_barrier(0);
}
// bar2: qpack LDS writes must be visible -> lgkmcnt(0) + s_barrier (still no vmcnt drain).
__device__ __forceinline__ void bar_lds() {
    asm volatile("s_waitcnt lgkmcnt(0)" ::: "memory");
    __builtin_amdgcn_sched_barrier(0);
    __builtin_amdgcn_s_barrier();
    __builtin_amdgcn_sched_barrier(0);
}

// ---------------- pass 1: per-block partial abs-max over x ----------------
__global__ __launch_bounds__(256) void k_amax_x(const float4* __restrict__ x4,
                                                float* __restrict__ partials, long n4) {
    float m = 0.f;
    long i = (long)blockIdx.x * blockDim.x + threadIdx.x;
    long stride = (long)gridDim.x * blockDim.x;
    for (; i < n4; i += stride) {
        float4 v = x4[i];
        m = fmaxf(m, fmaxf(fmaxf(fabsf(v.x), fabsf(v.y)), fmaxf(fabsf(v.z), fabsf(v.w))));
    }
    for (int o = 32; o > 0; o >>= 1) m = fmaxf(m, __shfl_xor(m, o));
    __shared__ float sm[4];
    if ((threadIdx.x & 63) == 0) sm[threadIdx.x >> 6] = m;
    __syncthreads();
    if (threadIdx.x == 0)
        partials[blockIdx.x] = fmaxf(fmaxf(sm[0], sm[1]), fmaxf(sm[2], sm[3]));
}

// ---------------- finalize amax; quantize + rearrange weights (1 block) ----------
// qw byte for (kh, o, k=kw*32+ci) at kh*8192 + o*128 + k;  k in [96,128) stays zero
__global__ __launch_bounds__(256) void k_quant_w(const float* __restrict__ w,
                                                 const float* __restrict__ partials,
                                                 signed char* __restrict__ qw,
                                                 float* __restrict__ amax_pair) {
    __shared__ __align__(16) signed char qs[24576];
    __shared__ float smx[4], smw[4];
    __shared__ float s_ax, s_aw;
    int t = threadIdx.x;
    for (int i = t; i < 1536; i += 256) ((v4i*)qs)[i] = (v4i){0, 0, 0, 0};

    float mx = 0.f;
    for (int i = t; i < AMAX_BLOCKS; i += 256) mx = fmaxf(mx, partials[i]);
    float mw = 0.f;
    const float4* w4 = (const float4*)w;
    for (int i = t; i < 4608; i += 256) {
        float4 v = w4[i];
        mw = fmaxf(mw, fmaxf(fmaxf(fabsf(v.x), fabsf(v.y)), fmaxf(fabsf(v.z), fabsf(v.w))));
    }
    for (int o = 32; o > 0; o >>= 1) {
        mx = fmaxf(mx, __shfl_xor(mx, o));
        mw = fmaxf(mw, __shfl_xor(mw, o));
    }
    if ((t & 63) == 0) { smx[t >> 6] = mx; smw[t >> 6] = mw; }
    __syncthreads();
    if (t == 0) {
        s_ax = fmaxf(fmaxf(smx[0], smx[1]), fmaxf(smx[2], smx[3]));
        s_aw = fmaxf(fmaxf(smw[0], smw[1]), fmaxf(smw[2], smw[3]));
        amax_pair[0] = s_ax;
        amax_pair[1] = s_aw;
    }
    __syncthreads();
    float s = 127.0f / s_aw;
    for (int i4 = t; i4 < 4608; i4 += 256) {
        float4 v = w4[i4];
        float e[4] = {v.x, v.y, v.z, v.w};
#pragma unroll
        for (int j = 0; j < 4; j++) {
            int idx = i4 * 4 + j;
            int kw = idx % 3;
            int kh = (idx / 3) % 3;
            int ci = (idx / 9) % 32;
            int o  = idx / 288;          // OIHW: ((o*32+ci)*3+kh)*3+kw
            float q = rintf(e[j] * s);
            q = fminf(127.f, fmaxf(-127.f, q));
            qs[kh * 8192 + o * 128 + kw * 32 + ci] = (signed char)q;
        }
    }
    __syncthreads();
    for (int i = t; i < 1536; i += 256) ((v4i*)qw)[i] = ((const v4i*)qs)[i];
}

// quantize 4 ci-planes worth of float4 and write 4 packed dwords into the swizzled ring
__device__ __forceinline__ void qpack_write(const float4 (&v)[4], bool valid, int gh,
                                            int cw, int cbase, float s_x,
                                            signed char* __restrict__ ldsb) {
    int pk[4] = {0, 0, 0, 0};
    if (valid) {
#pragma unroll
        for (int l = 0; l < 4; l++) {
            int q0 = (int)rintf(fminf(127.f, fmaxf(-127.f, v[l].x * s_x)));
            int q1 = (int)rintf(fminf(127.f, fmaxf(-127.f, v[l].y * s_x)));
            int q2 = (int)rintf(fminf(127.f, fmaxf(-127.f, v[l].z * s_x)));
            int q3 = (int)rintf(fminf(127.f, fmaxf(-127.f, v[l].w * s_x)));
            pk[0] |= (q0 & 255) << (8 * l);
            pk[1] |= (q1 & 255) << (8 * l);
            pk[2] |= (q2 & 255) << (8 * l);
            pk[3] |= (q3 & 255) << (8 * l);
        }
    }
#pragma unroll
    for (int j = 0; j < 4; j++)
        *(int*)&ldsb[swz((((gh & 3) * 120) + cw * 4 + j) * 32 + cbase)] = pk[j];
}

// ---------------- conv: fused x-quantize + implicit GEMM over a 28-row strip ----------
// block = (n, w-half 112, 28 output rows). 4-row LDS ring, weights in registers,
// per-wave epilogue patch, nontemporal out stores. grid = 32*2*8 = 512.
// Main-loop barriers are raw (no vmcnt(0) drain of the store stream).
__global__ __launch_bounds__(256) void k_conv(const float* __restrict__ x,
                                              const signed char* __restrict__ qw,
                                              const float* __restrict__ bias,
                                              const float* __restrict__ amax_pair,
                                              float* __restrict__ out) {
    __shared__ __align__(16) signed char lds[4 * 120 * 32 + 4 * 16 * 116 * 4];  // ring 15360 + ep 29696
    float* ep = (float*)(lds + 15360);

    int b = blockIdx.x;
    int wt = b & 1;
    int hs = (b >> 1) & 7;
    int n = b >> 4;
    int w0 = wt * 112;
    int hstart = hs * 28;
    int t = threadIdx.x;
    int lane = t & 63;
    int wv = t >> 6;
    int r = lane & 15;
    int chunk = lane >> 4;
    int cout = wv * 16 + r;

    float ax = amax_pair[0];
    float aw = amax_pair[1];
    float s_x = 127.0f / ax;
    float scale = (127.0f / ax) * (127.0f / aw);
    float invs = 1.0f / scale;
    float bv = bias[cout];

    // B fragments: load once from global (L2-hot), no LDS
    v4i bf[3][2];
#pragma unroll
    for (int dh = 0; dh < 3; dh++)
#pragma unroll
        for (int s = 0; s < 2; s++)
            bf[dh][s] = *(const v4i*)&qw[dh * 8192 + cout * 128 + s * 64 + chunk * 16];

    // prologue: stage rows hstart-1 .. hstart+2 (960 tasks = 4 rows x 30 cw x 8 quads)
#pragma unroll
    for (int k = 0; k < 4; k++) {
        int task = t + k * 256;
        if (task < 960) {
            int quad = task & 7;
            int rc = task >> 3;
            int cw = rc % 30;
            int row = rc / 30;
            int gh = hstart - 1 + row;
            int gw0 = w0 - 4 + cw * 4;
            int cbase = quad * 4;
            bool valid = ((unsigned)gh < 224u) && ((unsigned)gw0 < 224u);
            float4 v[4];
            if (valid) {
#pragma unroll
                for (int l = 0; l < 4; l++)
                    v[l] = *(const float4*)&x[((size_t)(n * CI + cbase + l) * HH + gh) * WW + gw0];
            }
            qpack_write(v, valid, gh, cw, cbase, s_x, lds);
        }
    }
    __syncthreads();

    float* epw = ep + wv * (16 * 116);

#pragma unroll 1
    for (int i = 0; i < 14; i++) {
        int h0 = hstart + 2 * i;
        bool pf = (i < 13);

        // T14 issue-early: global loads for rows h0+3, h0+4 (480 tasks: t and t+256 if t<224)
        float4 ldA[4], ldB[4];
        int ghA = 0, cwA = 0, cbA = 0, ghB = 0, cwB = 0, cbB = 0;
        bool vA = false, vB = false, hasB = (t < 224);
        if (pf) {
            {
                int task = t;
                int quad = task & 7;
                int rc = task >> 3;
                cwA = rc % 30;
                int row = rc / 30;
                ghA = h0 + 3 + row;
                int gw0 = w0 - 4 + cwA * 4;
                cbA = quad * 4;
                vA = ((unsigned)ghA < 224u) && ((unsigned)gw0 < 224u);
                if (vA) {
#pragma unroll
                    for (int l = 0; l < 4; l++)
                        ldA[l] = *(const float4*)&x[((size_t)(n * CI + cbA + l) * HH + ghA) * WW + gw0];
                }
            }
            if (hasB) {
                int task = t + 256;
                int quad = task & 7;
                int rc = task >> 3;
                cwB = rc % 30;
                int row = rc / 30;
                ghB = h0 + 3 + row;
                int gw0 = w0 - 4 + cwB * 4;
                cbB = quad * 4;
                vB = ((unsigned)ghB < 224u) && ((unsigned)gw0 < 224u);
                if (vB) {
#pragma unroll
                    for (int l = 0; l < 4; l++)
                        ldB[l] = *(const float4*)&x[((size_t)(n * CI + cbB + l) * HH + ghB) * WW + gw0];
                }
            }
        }

        // MFMA: 14 m-tiles (2 rows x 7 w-subtiles) x 6 K-steps
        v4i acc[14];
#pragma unroll
        for (int m = 0; m < 14; m++) acc[m] = (v4i){0, 0, 0, 0};
#pragma unroll
        for (int dh = 0; dh < 3; dh++) {
#pragma unroll
            for (int s = 0; s < 2; s++) {
                int k16 = s * 64 + chunk * 16;
                int dw = k16 >> 5;
                if (dw > 2) dw = 2;          // pad K: B zero, A addr just valid
                int cih = (k16 >> 4) & 1;
#pragma unroll
                for (int m = 0; m < 14; m++) {
                    int gh = h0 - 1 + (m / 7) + dh;
                    int wl = 3 + (m % 7) * 16 + r + dw;
                    v4i af = *(const v4i*)&lds[swz((((gh & 3) * 120) + wl) * 32 + cih * 16)];
                    acc[m] = __builtin_amdgcn_mfma_i32_16x16x64_i8(af, bf[dh][s], acc[m], 0, 0, 0);
                }
            }
        }

        // epilogue: per-wave LDS patch transpose + nontemporal coalesced stores
#pragma unroll
        for (int half = 0; half < 2; half++) {
#pragma unroll
            for (int mm = 0; mm < 7; mm++) {
                int m = half * 7 + mm;
                float4 o;
                o.x = fmaf((float)acc[m][0], invs, bv);
                o.y = fmaf((float)acc[m][1], invs, bv);
                o.z = fmaf((float)acc[m][2], invs, bv);
                o.w = fmaf((float)acc[m][3], invs, bv);
                *(float4*)&epw[r * 116 + mm * 16 + chunk * 4] = o;
            }
            int hh = h0 + half;
#pragma unroll
            for (int it = 0; it < 7; it++) {
                int idx = it * 64 + lane;
                int co = idx / 28;           // wave-local cout
                int w4i_ = (idx % 28) * 4;
                v4f v = *(const v4f*)&epw[co * 116 + w4i_];
                __builtin_nontemporal_store(v,
                    (v4f*)&out[(((size_t)n * CO + wv * 16 + co) * HH + hh) * WW + w0 + w4i_]);
            }
        }

        bar_nodrain();     // bar1: ring reads complete via MFMA data-dep; skip store drain

        // write-late: quantize prefetched rows into ring slots (h0+3, h0+4)
        if (pf) {
            qpack_write(ldA, vA, ghA, cwA, cbA, s_x, lds);
            if (hasB) qpack_write(ldB, vB, ghB, cwB, cbB, s_x, lds);
        }
        bar_lds();         // bar2: lgkmcnt(0) + s_barrier; new slots visible, still no store drain
    }
}

extern "C" void kernel_launch(void* const* d_in, const int* in_sizes, int n_in,
                              void* d_out, int out_size, void* d_ws, size_t ws_size,
                              hipStream_t stream) {
    const float* x = (const float*)d_in[0];
    const float* w = (const float*)d_in[1];
    const float* bias = (const float*)d_in[2];
    float* out = (float*)d_out;

    signed char* qw = (signed char*)d_ws;
    float* amax_pair = (float*)((char*)d_ws + AMAX_OFF);
    float* partials = (float*)((char*)d_ws + PART_OFF);

    long n4 = (long)BN * CI * HH * WW / 4;
    k_amax_x<<<AMAX_BLOCKS, 256, 0, stream>>>((const float4*)x, partials, n4);
    k_quant_w<<<1, 256, 0, stream>>>(w, partials, qw, amax_pair);
    k_conv<<<512, 256, 0, stream>>>(x, qw, bias, amax_pair, out);
}